// Round 1
// baseline (127.516 us; speedup 1.0000x reference)
//
#include <hip/hip_runtime.h>
#include <hip/hip_bf16.h>

#define C_DIM 256
#define B_SZ 32
#define NS 4096
#define NT_Z 256
#define TOPK_K 32
#define NWIN 64
#define WTOK 64

typedef __attribute__((ext_vector_type(8))) short short8;
typedef __attribute__((ext_vector_type(4))) float f32x4;

static __device__ inline unsigned short f2b(float f) {
  union { float f; unsigned int u; } x; x.f = f;
  unsigned int u = x.u;
  return (unsigned short)((u + 0x7FFFu + ((u >> 16) & 1u)) >> 16);
}
static __device__ inline float b2f(unsigned short h) {
  union { unsigned int u; float f; } x; x.u = ((unsigned int)h) << 16;
  return x.f;
}

// ---------------- kernel 1: weights f32 -> bf16 ----------------
__global__ void cvt_weights(const float* __restrict__ Wd, const float* __restrict__ Wu,
                            unsigned short* __restrict__ Wdb, unsigned short* __restrict__ Wub) {
  int i = blockIdx.x * 256 + threadIdx.x;   // 65536 elements each
  Wdb[i] = f2b(Wd[i]);
  Wub[i] = f2b(Wu[i]);
}

// ---------------- kernel 2: z_max over Nt ----------------
__global__ void zmax_kernel(const float* __restrict__ z, float* __restrict__ zmax) {
  int b = blockIdx.x;
  int c = threadIdx.x;
  const float* p = z + (size_t)b * NT_Z * C_DIM + c;
  float m = p[0];
  for (int n = 1; n < NT_Z; ++n) m = fmaxf(m, p[(size_t)n * C_DIM]);
  zmax[b * C_DIM + c] = m;
}

// ---------------- kernel 3: window scores ----------------
// score[b][w] = sum over 64 tokens of dot(zmax[b], x[b][n]).  (scale factors
// dropped -- only the ranking matters).  Sum token rows per-lane first, one
// dot at the end.
__global__ __launch_bounds__(256) void winscore_kernel(const float* __restrict__ x,
                                                       const float* __restrict__ zmax,
                                                       float* __restrict__ score) {
  int b = blockIdx.x >> 6;
  int w = blockIdx.x & 63;
  int wy = w >> 3, wx = w & 7;

  __shared__ float zs[C_DIM];
  zs[threadIdx.x] = zmax[b * C_DIM + threadIdx.x];
  __syncthreads();

  int wv = threadIdx.x >> 6;
  int ln = threadIdx.x & 63;

  float a0 = 0.f, a1 = 0.f, a2 = 0.f, a3 = 0.f;
  for (int t = 0; t < 16; ++t) {
    int tok = wv * 16 + t;
    int iy = tok >> 3, ix = tok & 7;
    int n = (wy * 8 + iy) * 64 + wx * 8 + ix;
    const float4 v = *(const float4*)(x + ((size_t)b * NS + n) * C_DIM + ln * 4);
    a0 += v.x; a1 += v.y; a2 += v.z; a3 += v.w;
  }
  const float4 z4 = ((const float4*)zs)[ln];
  float p = a0 * z4.x + a1 * z4.y + a2 * z4.z + a3 * z4.w;
  for (int off = 32; off >= 1; off >>= 1) p += __shfl_xor(p, off);

  __shared__ float wsum[4];
  if (ln == 0) wsum[wv] = p;
  __syncthreads();
  if (threadIdx.x == 0) score[blockIdx.x] = wsum[0] + wsum[1] + wsum[2] + wsum[3];
}

// ---------------- kernel 4: top-32 of 64, jax.lax.top_k order ----------------
__global__ void topk_kernel(const float* __restrict__ score, int* __restrict__ idx) {
  int b = blockIdx.x;
  int w = threadIdx.x;  // 64 threads
  __shared__ float s[NWIN];
  float v = score[b * NWIN + w];
  s[w] = v;
  __syncthreads();
  int rank = 0;
  for (int j = 0; j < NWIN; ++j) {
    float sj = s[j];
    rank += (sj > v) || (sj == v && j < w);
  }
  if (rank < TOPK_K) idx[b * TOPK_K + rank] = w;
}

// ---------------- kernel 5: fused gather + GEMM1 + shift + GEMM2 + add ------
// one block per (b, k).  4 waves; wave wv owns output-channel tiles
// [wv*64, wv*64+64) as 4 n-tiles x 4 m-tiles of 16x16x32 bf16 MFMA.
// LDS tiles are XOR-swizzled:  byte_in_row ^= (row & 7) << 4.
__global__ __launch_bounds__(256) void fused_win(
    const float* __restrict__ x, const int* __restrict__ idx,
    const unsigned short* __restrict__ Wdb, const unsigned short* __restrict__ Wub,
    const float* __restrict__ bd, const float* __restrict__ bu,
    float* __restrict__ out)
{
  __shared__ unsigned short xe_s[WTOK * C_DIM];  // 32 KB
  __shared__ unsigned short t_s[WTOK * C_DIM];   // 32 KB

  const int bk = blockIdx.x;
  const int b = bk >> 5;
  const int kk = bk & 31;
  const int wsel = idx[b * TOPK_K + kk];
  const int wy = wsel >> 3, wx = wsel & 7;

  // ---- stage xe (window tokens) as bf16, swizzled ----
  #pragma unroll
  for (int i = 0; i < 16; ++i) {
    int f = threadIdx.x + i * 256;   // float4 id 0..4095
    int m = f >> 6, c4 = f & 63;
    int iy = m >> 3, ix = m & 7;
    int n = (wy * 8 + iy) * 64 + wx * 8 + ix;
    const float4 v = *(const float4*)(x + ((size_t)b * NS + n) * C_DIM + c4 * 4);
    ushort4 h;
    h.x = f2b(v.x); h.y = f2b(v.y); h.z = f2b(v.z); h.w = f2b(v.w);
    int byteoff = m * 512 + ((c4 * 8) ^ ((m & 7) << 4));
    *(ushort4*)((char*)xe_s + byteoff) = h;
  }
  __syncthreads();

  const int wv = threadIdx.x >> 6;
  const int ln = threadIdx.x & 63;
  const int lr = ln & 15;   // A-row / B-col / D-col
  const int lg = ln >> 4;   // k-subgroup

  // ---- GEMM1: t = xe @ Wd^T ----
  f32x4 acc[4][4];
  #pragma unroll
  for (int a = 0; a < 4; ++a)
    #pragma unroll
    for (int n2 = 0; n2 < 4; ++n2) acc[a][n2] = (f32x4){0.f, 0.f, 0.f, 0.f};

  for (int ks = 0; ks < 8; ++ks) {
    const int kb = ks * 64 + lg * 16;   // byte offset of k within a row
    const int krow = ks * 32 + lg * 8;  // element k
    short8 af[4];
    #pragma unroll
    for (int mt = 0; mt < 4; ++mt) {
      int m = mt * 16 + lr;
      af[mt] = *(const short8*)((const char*)xe_s + m * 512 + (kb ^ ((m & 7) << 4)));
    }
    short8 bf[4];
    #pragma unroll
    for (int nt = 0; nt < 4; ++nt) {
      int o = (wv * 4 + nt) * 16 + lr;
      bf[nt] = *(const short8*)(Wdb + o * C_DIM + krow);
    }
    #pragma unroll
    for (int mt = 0; mt < 4; ++mt)
      #pragma unroll
      for (int nt = 0; nt < 4; ++nt)
        acc[mt][nt] = __builtin_amdgcn_mfma_f32_16x16x32_bf16(af[mt], bf[nt], acc[mt][nt], 0, 0, 0);
  }

  // ---- epilogue 1: t = acc + bd -> bf16 -> t_s (swizzled) ----
  #pragma unroll
  for (int nt = 0; nt < 4; ++nt) {
    int o = (wv * 4 + nt) * 16 + lr;
    float bdv = bd[o];
    #pragma unroll
    for (int mt = 0; mt < 4; ++mt) {
      #pragma unroll
      for (int r = 0; r < 4; ++r) {
        int m = mt * 16 + lg * 4 + r;
        float v = acc[mt][nt][r] + bdv;
        *(unsigned short*)((char*)t_s + m * 512 + ((o * 2) ^ ((m & 7) << 4))) = f2b(v);
      }
    }
  }
  __syncthreads();

  // ---- GEMM2: up = shift(t) @ Wu^T ----
  f32x4 acc2[4][4];
  #pragma unroll
  for (int a = 0; a < 4; ++a)
    #pragma unroll
    for (int n2 = 0; n2 < 4; ++n2) acc2[a][n2] = (f32x4){0.f, 0.f, 0.f, 0.f};

  for (int ks = 0; ks < 8; ++ks) {
    const int g = ks >> 1;              // channel group (64-wide), uniform per ks
    const int kb = ks * 64 + lg * 16;
    const int krow = ks * 32 + lg * 8;
    short8 af[4];
    #pragma unroll
    for (int mt = 0; mt < 4; ++mt) {
      int m = mt * 16 + lr;
      int iy = m >> 3, ix = m & 7;
      int ms; bool ok;
      if (g == 0)      { ok = (ix < 7); ms = m + 1; }
      else if (g == 1) { ok = (ix > 0); ms = m - 1; }
      else if (g == 2) { ok = (iy < 7); ms = m + 8; }
      else             { ok = (iy > 0); ms = m - 8; }
      short8 v = {0, 0, 0, 0, 0, 0, 0, 0};
      if (ok) v = *(const short8*)((const char*)t_s + ms * 512 + (kb ^ ((ms & 7) << 4)));
      af[mt] = v;
    }
    short8 bf[4];
    #pragma unroll
    for (int nt = 0; nt < 4; ++nt) {
      int o = (wv * 4 + nt) * 16 + lr;
      bf[nt] = *(const short8*)(Wub + o * C_DIM + krow);
    }
    #pragma unroll
    for (int mt = 0; mt < 4; ++mt)
      #pragma unroll
      for (int nt = 0; nt < 4; ++nt)
        acc2[mt][nt] = __builtin_amdgcn_mfma_f32_16x16x32_bf16(af[mt], bf[nt], acc2[mt][nt], 0, 0, 0);
  }

  // ---- epilogue 2: out = xe + up + bu ----
  const size_t obase = (size_t)bk * WTOK * C_DIM;
  #pragma unroll
  for (int nt = 0; nt < 4; ++nt) {
    int c = (wv * 4 + nt) * 16 + lr;
    float buv = bu[c];
    #pragma unroll
    for (int mt = 0; mt < 4; ++mt) {
      #pragma unroll
      for (int r = 0; r < 4; ++r) {
        int m = mt * 16 + lg * 4 + r;
        unsigned short xb =
            *(const unsigned short*)((const char*)xe_s + m * 512 + ((c * 2) ^ ((m & 7) << 4)));
        out[obase + (size_t)m * C_DIM + c] = b2f(xb) + acc2[mt][nt][r] + buv;
      }
    }
  }
}

// ---------------- launch ----------------
extern "C" void kernel_launch(void* const* d_in, const int* in_sizes, int n_in,
                              void* d_out, int out_size, void* d_ws, size_t ws_size,
                              hipStream_t stream) {
  const float* z  = (const float*)d_in[0];
  const float* x  = (const float*)d_in[1];
  const float* Wd = (const float*)d_in[2];
  const float* bd = (const float*)d_in[3];
  const float* Wu = (const float*)d_in[4];
  const float* bu = (const float*)d_in[5];
  float* out = (float*)d_out;

  char* ws = (char*)d_ws;
  unsigned short* Wdb = (unsigned short*)(ws);            // 131072 B
  unsigned short* Wub = (unsigned short*)(ws + 131072);   // 131072 B
  float* zmax  = (float*)(ws + 262144);                   // 32 KB
  float* score = (float*)(ws + 294912);                   // 8 KB
  int*   idx   = (int*)(ws + 303104);                     // 4 KB

  hipLaunchKernelGGL(cvt_weights, dim3(256), dim3(256), 0, stream, Wd, Wu, Wdb, Wub);
  hipLaunchKernelGGL(zmax_kernel, dim3(B_SZ), dim3(C_DIM), 0, stream, z, zmax);
  hipLaunchKernelGGL(winscore_kernel, dim3(B_SZ * NWIN), dim3(256), 0, stream, x, zmax, score);
  hipLaunchKernelGGL(topk_kernel, dim3(B_SZ), dim3(NWIN), 0, stream, score, idx);
  hipLaunchKernelGGL(fused_win, dim3(B_SZ * TOPK_K), dim3(256), 0, stream,
                     x, idx, Wdb, Wub, bd, bu, out);
}